// Round 1
// baseline (95.311 us; speedup 1.0000x reference)
//
#include <hip/hip_runtime.h>
#include <hip/hip_bf16.h>

// Problem: B=16384, C=32, S=12 symmetry-aware geodesic rotation loss.
// tr(R_pred @ (rot_s @ R_gt)^T) = <R_pred @ R_gt^T, rot_s>  (Frobenius dot)
// min over theta == acos(clip(max over tr)) since acos(clip(.)) is monotone
// non-increasing. So: per (b,c): M = R_pred @ R_gt^T (27 FMA), 12 dots vs
// rot_s, max over (c,s), one acos per b, mean over b.

#define BPB 8           // batch elements per block
#define BLOCK 256       // 8 b * 32 c
#define NB 16384
#define NC 32
#define NS 12

__global__ __launch_bounds__(BLOCK) void sym_loss_kernel(
    const float* __restrict__ R_pred,   // (B, C, 3, 3)
    const float* __restrict__ R_gt,     // (B, 3, 3)
    const float* __restrict__ rot,      // (S, 3, 3)
    float* __restrict__ out)            // scalar accumulator (pre-zeroed)
{
    __shared__ float s_rot[NS * 9];          // 108
    __shared__ float s_gt[BPB * 9];          // 72
    __shared__ float s_pred[BPB * NC * 9];   // 2304 floats = 9216 B
    __shared__ float s_theta[BPB];

    const int tid = threadIdx.x;
    const int b0 = blockIdx.x * BPB;

    if (tid < NS * 9) s_rot[tid] = rot[tid];
    if (tid < BPB * 9) s_gt[tid] = R_gt[(size_t)b0 * 9 + tid];

    // Stage this block's R_pred chunk (2304 floats, 16B-aligned) via float4.
    const float4* src = (const float4*)(R_pred + (size_t)b0 * NC * 9);
    float4* dst = (float4*)s_pred;
    #pragma unroll
    for (int i = tid; i < (BPB * NC * 9) / 4; i += BLOCK) dst[i] = src[i];
    __syncthreads();

    const int lb = tid >> 5;                   // local b  [0,8)
    const float* P = &s_pred[tid * 9];         // stride 9 (odd) -> conflict-free
    const float* G = &s_gt[lb * 9];            // same addr across 32 lanes -> broadcast

    // M = R_pred @ R_gt^T : M[i][j] = sum_k P[i,k] * G[j,k]
    float M[9];
    #pragma unroll
    for (int i = 0; i < 3; ++i)
        #pragma unroll
        for (int j = 0; j < 3; ++j)
            M[i * 3 + j] = fmaf(P[i * 3 + 0], G[j * 3 + 0],
                           fmaf(P[i * 3 + 1], G[j * 3 + 1],
                                P[i * 3 + 2] * G[j * 3 + 2]));

    float mx = -1e30f;
    #pragma unroll
    for (int s = 0; s < NS; ++s) {
        const float* R = &s_rot[s * 9];        // broadcast
        float tr = 0.0f;
        #pragma unroll
        for (int e = 0; e < 9; ++e) tr = fmaf(M[e], R[e], tr);
        mx = fmaxf(mx, tr);
    }

    // max across the 32 c-lanes sharing this b (xor masks < 32 stay in-half)
    #pragma unroll
    for (int m = 1; m < 32; m <<= 1) mx = fmaxf(mx, __shfl_xor(mx, m, 64));

    if ((tid & 31) == 0) {
        const float lo = (float)(-1.0 + 1e-7);  // matches ref rounding
        const float hi = (float)( 1.0 - 1e-7);
        float cosv = fminf(fmaxf((mx - 1.0f) * 0.5f, lo), hi);
        s_theta[lb] = acosf(cosv);
    }
    __syncthreads();

    if (tid == 0) {
        float acc = 0.0f;
        #pragma unroll
        for (int i = 0; i < BPB; ++i) acc += s_theta[i];
        atomicAdd(out, acc * (1.0f / (float)NB));
    }
}

extern "C" void kernel_launch(void* const* d_in, const int* in_sizes, int n_in,
                              void* d_out, int out_size, void* d_ws, size_t ws_size,
                              hipStream_t stream) {
    const float* R_pred = (const float*)d_in[0];
    const float* R_gt   = (const float*)d_in[1];
    const float* rot    = (const float*)d_in[2];
    float* out = (float*)d_out;

    hipMemsetAsync(out, 0, sizeof(float), stream);  // d_out poisoned each call

    dim3 grid(NB / BPB);   // 2048 blocks
    dim3 block(BLOCK);
    sym_loss_kernel<<<grid, block, 0, stream>>>(R_pred, R_gt, rot, out);
}

// Round 2
// 72.347 us; speedup vs baseline: 1.3174x; 1.3174x over previous
//
#include <hip/hip_runtime.h>
#include <hip/hip_bf16.h>

// B=16384, C=32, S=12 symmetry-aware geodesic rotation loss.
// tr(R_pred @ (rot_s @ R_gt)^T) = <R_pred @ R_gt^T, rot_s>  (Frobenius dot)
// min_s,c theta == acos(clip(max_{s,c} tr)) since acos(clip(.)) is monotone
// non-increasing. Per (b,c): M = R_pred @ R_gt^T (27 FMA), 12 dots vs rot_s,
// max over (c,s), one acos per b, mean over b.
//
// R2: no memset, no atomics — per-block partials to d_ws (plain stores),
// second 1-block kernel reduces 2048 partials and writes the mean.

#define BPB 8           // batch elements per block
#define BLOCK 256       // 8 b * 32 c
#define NB 16384
#define NC 32
#define NS 12
#define NBLK (NB / BPB) // 2048 partials

__global__ __launch_bounds__(BLOCK) void sym_loss_main(
    const float* __restrict__ R_pred,   // (B, C, 3, 3)
    const float* __restrict__ R_gt,     // (B, 3, 3)
    const float* __restrict__ rot,      // (S, 3, 3)
    float* __restrict__ partial)        // (NBLK)
{
    __shared__ float s_rot[NS * 9];          // 108
    __shared__ float s_gt[BPB * 9];          // 72
    __shared__ float s_pred[BPB * NC * 9];   // 2304 floats = 9216 B
    __shared__ float s_theta[BPB];

    const int tid = threadIdx.x;
    const int b0 = blockIdx.x * BPB;

    if (tid < NS * 9) s_rot[tid] = rot[tid];
    if (tid < BPB * 9) s_gt[tid] = R_gt[(size_t)b0 * 9 + tid];

    // Stage this block's R_pred chunk (2304 floats, 16B-aligned) via float4.
    const float4* src = (const float4*)(R_pred + (size_t)b0 * NC * 9);
    float4* dst = (float4*)s_pred;
    #pragma unroll
    for (int i = tid; i < (BPB * NC * 9) / 4; i += BLOCK) dst[i] = src[i];
    __syncthreads();

    const int lb = tid >> 5;                   // local b  [0,8)
    const float* P = &s_pred[tid * 9];         // stride 9 (odd) -> conflict-free
    const float* G = &s_gt[lb * 9];            // same addr across 32 lanes -> broadcast

    // M = R_pred @ R_gt^T : M[i][j] = sum_k P[i,k] * G[j,k]
    float M[9];
    #pragma unroll
    for (int i = 0; i < 3; ++i)
        #pragma unroll
        for (int j = 0; j < 3; ++j)
            M[i * 3 + j] = fmaf(P[i * 3 + 0], G[j * 3 + 0],
                           fmaf(P[i * 3 + 1], G[j * 3 + 1],
                                P[i * 3 + 2] * G[j * 3 + 2]));

    float mx = -1e30f;
    #pragma unroll
    for (int s = 0; s < NS; ++s) {
        const float* R = &s_rot[s * 9];        // broadcast
        float tr = 0.0f;
        #pragma unroll
        for (int e = 0; e < 9; ++e) tr = fmaf(M[e], R[e], tr);
        mx = fmaxf(mx, tr);
    }

    // max across the 32 c-lanes sharing this b (xor masks < 32 stay in-half)
    #pragma unroll
    for (int m = 1; m < 32; m <<= 1) mx = fmaxf(mx, __shfl_xor(mx, m, 64));

    if ((tid & 31) == 0) {
        const float lo = (float)(-1.0 + 1e-7);
        const float hi = (float)( 1.0 - 1e-7);
        float cosv = fminf(fmaxf((mx - 1.0f) * 0.5f, lo), hi);
        s_theta[lb] = acosf(cosv);
    }
    __syncthreads();

    if (tid == 0) {
        float acc = 0.0f;
        #pragma unroll
        for (int i = 0; i < BPB; ++i) acc += s_theta[i];
        partial[blockIdx.x] = acc;             // plain store, no init needed
    }
}

__global__ __launch_bounds__(256) void sym_loss_reduce(
    const float* __restrict__ partial,  // (NBLK)
    float* __restrict__ out)            // scalar
{
    __shared__ float s_wave[4];
    const int tid = threadIdx.x;

    float acc = 0.0f;
    #pragma unroll
    for (int i = 0; i < NBLK / 256; ++i) acc += partial[tid + i * 256];

    #pragma unroll
    for (int m = 1; m < 64; m <<= 1) acc += __shfl_xor(acc, m, 64);

    if ((tid & 63) == 0) s_wave[tid >> 6] = acc;
    __syncthreads();

    if (tid == 0) {
        float t = s_wave[0] + s_wave[1] + s_wave[2] + s_wave[3];
        *out = t * (1.0f / (float)NB);
    }
}

extern "C" void kernel_launch(void* const* d_in, const int* in_sizes, int n_in,
                              void* d_out, int out_size, void* d_ws, size_t ws_size,
                              hipStream_t stream) {
    const float* R_pred = (const float*)d_in[0];
    const float* R_gt   = (const float*)d_in[1];
    const float* rot    = (const float*)d_in[2];
    float* out = (float*)d_out;
    float* partial = (float*)d_ws;

    sym_loss_main<<<dim3(NBLK), dim3(BLOCK), 0, stream>>>(R_pred, R_gt, rot, partial);
    sym_loss_reduce<<<dim3(1), dim3(256), 0, stream>>>(partial, out);
}